// Round 1
// baseline (4143.248 us; speedup 1.0000x reference)
//
#include <hip/hip_runtime.h>
#include <math.h>

#define BB 8
#define NCLS 21
#define NANCH 2048
#define FH 32
#define FW 64
#define TOPK_N 100

// ---------------- workspace layout (bytes) ----------------
// region A (0..64MB) is reused after conv3 for all post-feat buffers.
static const size_t OFF_X1    = 0;          // 8*64*128*256*4 = 67108864
static const size_t OFF_X2    = 67108864;   // 8*128*64*128*4 = 33554432
static const size_t OFF_FEAT  = 100663296;  // 8*256*32*64*4  = 16777216
static const size_t OFF_P1    = 0;          // 16777216 (reuse of X1)
static const size_t OFF_PROTO = 16777216;   // 8*32*2048*4 = 2097152
static const size_t OFF_CLS   = 18874368;   // 8*21*2048*4 = 1376256
static const size_t OFF_BOXH  = 20250624;   // 8*4*2048*4  = 262144
static const size_t OFF_COEF  = 20512768;   // 8*32*2048*4 = 2097152
static const size_t OFF_BOXES = 22609920;   // 8*2048*4*4  = 262144
static const size_t OFF_SCORES= 22872064;   // 8*2048*4    = 65536
static const size_t OFF_LABELS= 22937600;   // 8*2048*4    = 65536 (int)
static const size_t OFF_ORDER = 23003136;   // 8*2048*4    = 65536 (int)
static const size_t OFF_SB    = 23068672;   // 8*2048*4*4  = 262144
static const size_t OFF_IOU   = 23330816;   // 8*2048*32*8 = 4194304 (u64)
static const size_t OFF_KEEP  = 27525120;   // 8*100*4     = 3200 (int)
static const size_t OFF_MAXB  = 27528320;   // 8*4         = 32 (uint)
static const size_t OFF_M     = 27528448;   // 8*100*2048*4= 6553600

// ---------------- output layout (float elements) ----------------
static const size_t OUT_BOXES  = 0;          // 8*100*4 = 3200
static const size_t OUT_SCORES = 3200;       // 800
static const size_t OUT_LABELS = 4000;       // 800
static const size_t OUT_MASKS  = 4800;       // 8*100*256*512 = 104857600
static const size_t OUT_VALID  = 104862400;  // 800

__device__ __forceinline__ unsigned encf(float f){
  unsigned u = __float_as_uint(f);
  return (u & 0x80000000u) ? ~u : (u | 0x80000000u);
}
__device__ __forceinline__ float decf(unsigned u){
  unsigned b = (u & 0x80000000u) ? (u & 0x7fffffffu) : ~u;
  return __uint_as_float(b);
}

__global__ void initk(unsigned* maxb){
  if (threadIdx.x < BB) maxb[threadIdx.x] = 0u;
}

// ---------------- direct 3x3 conv, COPT output channels / thread ----------------
template<int CIN,int COUT,int H,int W,int OH,int OW,int S,int COPT,bool RELU>
__global__ void convk(const float* __restrict__ in, const float* __restrict__ wgt,
                      const float* __restrict__ bias, float* __restrict__ out) {
  extern __shared__ float wlds[];               // COPT*CIN*9
  const int b   = blockIdx.z;
  const int co0 = blockIdx.y * COPT;
  const int tid = threadIdx.x;
  for (int i = tid; i < COPT*CIN*9; i += blockDim.x)
    wlds[i] = wgt[(size_t)co0*CIN*9 + i];
  __syncthreads();
  const int sp = blockIdx.x * blockDim.x + tid;
  if (sp >= OH*OW) return;
  const int oy = sp / OW, ox = sp % OW;
  float acc[COPT];
#pragma unroll
  for (int c=0;c<COPT;c++) acc[c] = bias[co0+c];
  int iy[3], ix[3]; bool vy[3], vx[3];
#pragma unroll
  for (int k=0;k<3;k++){
    iy[k]=oy*S-1+k; vy[k]=(iy[k]>=0)&&(iy[k]<H);
    ix[k]=ox*S-1+k; vx[k]=(ix[k]>=0)&&(ix[k]<W);
  }
  const float* inb = in + (size_t)b*CIN*H*W;
  for (int ci=0;ci<CIN;ci++){
    const float* inc = inb + (size_t)ci*H*W;
    const float* wl  = wlds + ci*9;
#pragma unroll
    for (int kh=0;kh<3;kh++){
      if (!vy[kh]) continue;
      const float* rp = inc + iy[kh]*W;
#pragma unroll
      for (int kw=0;kw<3;kw++){
        if (!vx[kw]) continue;
        float v = rp[ix[kw]];
#pragma unroll
        for (int c=0;c<COPT;c++)
          acc[c] = fmaf(v, wl[c*CIN*9 + kh*3 + kw], acc[c]);
      }
    }
  }
#pragma unroll
  for (int c=0;c<COPT;c++){
    float r = RELU ? fmaxf(acc[c], 0.f) : acc[c];
    out[((size_t)b*COUT + co0 + c)*((size_t)OH*OW) + sp] = r;
  }
}

// ---------------- 1x1 conv: p1[8,256,2048] -> proto[8,32,2048] ----------------
__global__ void pw2k(const float* __restrict__ p1, const float* __restrict__ w,
                     const float* __restrict__ bias, float* __restrict__ proto){
  __shared__ float wl[32*256];
  __shared__ float bl[32];
  const int b = blockIdx.y, tid = threadIdx.x;
  for (int i = tid; i < 32*256; i += blockDim.x) wl[i] = w[i];
  if (tid < 32) bl[tid] = bias[tid];
  __syncthreads();
  const int sp = blockIdx.x*blockDim.x + tid;   // 0..2047
  float acc[32];
#pragma unroll
  for (int c=0;c<32;c++) acc[c] = bl[c];
  const float* pb = p1 + (size_t)b*256*NANCH + sp;
  for (int ci=0;ci<256;ci++){
    float v = pb[(size_t)ci*NANCH];
#pragma unroll
    for (int c=0;c<32;c++) acc[c] = fmaf(v, wl[c*256+ci], acc[c]);
  }
#pragma unroll
  for (int c=0;c<32;c++)
    proto[((size_t)b*32 + c)*NANCH + sp] = acc[c];
}

// ---------------- decode: softmax/labels/boxes + per-batch max(boxes) ----------------
__global__ void decodek(const float* __restrict__ cls, const float* __restrict__ boxh,
                        float* __restrict__ boxes, float* __restrict__ scores,
                        int* __restrict__ labels, unsigned* __restrict__ maxb){
  const int b = blockIdx.y;
  const int n = blockIdx.x*blockDim.x + threadIdx.x;  // 0..2047
  const float* cp = cls + (size_t)b*NCLS*NANCH + n;
  float l[NCLS];
  float M = -1e30f;
#pragma unroll
  for (int c=0;c<NCLS;c++){ l[c] = cp[(size_t)c*NANCH]; M = fmaxf(M, l[c]); }
  float denom = 0.f;
#pragma unroll
  for (int c=0;c<NCLS;c++) denom += expf(l[c]-M);
  float best = -1.f; int bi = 0;
#pragma unroll
  for (int c=0;c<NCLS-1;c++){
    float e = expf(l[c]-M);
    if (e > best){ best = e; bi = c; }
  }
  scores[(size_t)b*NANCH + n] = best/denom;
  labels[(size_t)b*NANCH + n] = bi;

  const float* bh = boxh + (size_t)b*4*NANCH + n;
  float dx=bh[0], dy=bh[NANCH], dw=bh[2*NANCH], dh=bh[3*NANCH];
  const int yy = n >> 6, xx = n & 63;
  float cx = (xx+0.5f)*8.f, cy = (yy+0.5f)*8.f;
  float px = cx + dx*32.f, py = cy + dy*32.f;
  float pw = 32.f*expf(dw), ph = 32.f*expf(dh);
  float x1 = px - 0.5f*pw, y1 = py - 0.5f*ph;
  float x2 = px + 0.5f*pw, y2 = py + 0.5f*ph;
  float* bo = boxes + ((size_t)b*NANCH + n)*4;
  bo[0]=x1; bo[1]=y1; bo[2]=x2; bo[3]=y2;
  float mx = fmaxf(fmaxf(x1,y1), fmaxf(x2,y2));
#pragma unroll
  for (int off=32; off>0; off>>=1) mx = fmaxf(mx, __shfl_down(mx, off));
  if ((threadIdx.x & 63) == 0) atomicMax(maxb + b, encf(mx));
}

// ---------------- stable descending sort (bitonic, idx tiebreak) ----------------
__global__ void __launch_bounds__(1024) sortk(const float* __restrict__ scores,
                     const float* __restrict__ boxes, const int* __restrict__ labels,
                     const unsigned* __restrict__ maxb,
                     int* __restrict__ order, float* __restrict__ sb){
  __shared__ float sc[NANCH];
  __shared__ int   id[NANCH];
  const int b = blockIdx.x, t = threadIdx.x;
  for (int i=t;i<NANCH;i+=1024){ sc[i]=scores[(size_t)b*NANCH+i]; id[i]=i; }
  __syncthreads();
  for (int k=2;k<=NANCH;k<<=1){
    for (int j=k>>1;j>0;j>>=1){
      for (int i=t;i<NANCH;i+=1024){
        int ixj = i ^ j;
        if (ixj > i){
          float sa=sc[i], sb_=sc[ixj]; int ia=id[i], ib=id[ixj];
          bool dir = ((i & k) == 0);
          // before(x,y): x precedes y in desired order (score desc, idx asc)
          bool before_ba = (sb_ > sa) || (sb_ == sa && ib < ia);
          if (before_ba == dir){ sc[i]=sb_; sc[ixj]=sa; id[i]=ib; id[ixj]=ia; }
        }
      }
      __syncthreads();
    }
  }
  float mboff = decf(maxb[b]) + 1.0f;
  for (int r=t;r<NANCH;r+=1024){
    int o = id[r];
    order[(size_t)b*NANCH + r] = o;
    float off = (float)labels[(size_t)b*NANCH + o] * mboff;
    const float* bo = boxes + ((size_t)b*NANCH + o)*4;
    float* sp = sb + ((size_t)b*NANCH + r)*4;
    sp[0]=bo[0]+off; sp[1]=bo[1]+off; sp[2]=bo[2]+off; sp[3]=bo[3]+off;
  }
}

// ---------------- IoU>thr bitmask: rows = sorted i, 32 u64 words over j ----------------
__global__ void ioumask(const float* __restrict__ sb, unsigned long long* __restrict__ iou){
  const int b = blockIdx.y;
  const int gid = blockIdx.x*blockDim.x + threadIdx.x;  // 0..65535
  const int i = gid >> 5, w = gid & 31;
  const float* base = sb + (size_t)b*NANCH*4;
  unsigned long long bits = 0ull;
  const int j0 = w << 6;
  if (j0 + 63 > i){
    float x1=base[i*4], y1=base[i*4+1], x2=base[i*4+2], y2=base[i*4+3];
    float ai = (x2-x1)*(y2-y1);
    for (int jj=0;jj<64;jj++){
      int j = j0 + jj;
      if (j > i){
        float bx1=base[j*4], by1=base[j*4+1], bx2=base[j*4+2], by2=base[j*4+3];
        float lx=fmaxf(x1,bx1), ly=fmaxf(y1,by1);
        float rx=fminf(x2,bx2), ry=fminf(y2,by2);
        float ww=fmaxf(rx-lx,0.f), hh=fmaxf(ry-ly,0.f);
        float inter = ww*hh;
        float aj = (bx2-bx1)*(by2-by1);
        float v = inter/(ai + aj - inter + 1e-9f);
        if (v > 0.5f) bits |= (1ull << jj);
      }
    }
  }
  iou[((size_t)b*NANCH + i)*32 + w] = bits;
}

// ---------------- greedy NMS scan: 1 wave / batch, early exit at 100 keeps ----------------
__global__ void nmsscan(const unsigned long long* __restrict__ iou,
                        const int* __restrict__ order, int* __restrict__ keep){
  const int b = blockIdx.x, lane = threadIdx.x;  // 64 lanes
  unsigned long long sup = 0ull;                 // lanes 0..31 own words
  int k = 0;
  for (int i=0; i<NANCH && k<TOPK_N; i++){
    int wi = i >> 6, bi = i & 63;
    unsigned long long wv = __shfl(sup, wi);
    if (!((wv >> bi) & 1ull)){
      if (lane == 0) keep[b*TOPK_N + k] = order[(size_t)b*NANCH + i];
      k++;
      unsigned long long row = (lane < 32) ? iou[((size_t)b*NANCH + i)*32 + lane] : 0ull;
      sup |= row;
    }
  }
  for (int r = lane; r < TOPK_N; r += 64)
    if (r >= k) keep[b*TOPK_N + r] = -1;
}

// ---------------- gather kept boxes/scores/labels/valid to output ----------------
__global__ void gatherk(const int* __restrict__ keep, const float* __restrict__ boxes,
                        const float* __restrict__ scores, const int* __restrict__ labels,
                        float* __restrict__ out){
  const int b = blockIdx.x, r = threadIdx.x;
  if (r >= TOPK_N) return;
  int ki = keep[b*TOPK_N + r];
  float valid = (ki >= 0) ? 1.f : 0.f;
  int kc = (ki < 0) ? 0 : ki;
  const float* bo = boxes + ((size_t)b*NANCH + kc)*4;
#pragma unroll
  for (int c=0;c<4;c++) out[OUT_BOXES + ((size_t)b*TOPK_N + r)*4 + c] = bo[c]*valid;
  out[OUT_SCORES + b*TOPK_N + r] = scores[(size_t)b*NANCH + kc]*valid;
  out[OUT_LABELS + b*TOPK_N + r] = (ki >= 0) ? (float)labels[(size_t)b*NANCH + kc] : 0.f;
  out[OUT_VALID  + b*TOPK_N + r] = valid;
}

// ---------------- mask logits + sigmoid: m[b,r,2048] ----------------
__global__ void maskm(const int* __restrict__ keep, const float* __restrict__ coef,
                      const float* __restrict__ proto, float* __restrict__ m){
  const int b = blockIdx.z, r = blockIdx.y;
  const int s = blockIdx.x*blockDim.x + threadIdx.x;   // 0..2047
  __shared__ float cf[32];
  int ki = keep[b*TOPK_N + r];
  int kc = (ki < 0) ? 0 : ki;
  if (threadIdx.x < 32) cf[threadIdx.x] = coef[((size_t)b*32 + threadIdx.x)*NANCH + kc];
  __syncthreads();
  float acc = 0.f;
#pragma unroll
  for (int p=0;p<32;p++) acc = fmaf(cf[p], proto[((size_t)b*32 + p)*NANCH + s], acc);
  m[((size_t)b*TOPK_N + r)*NANCH + s] = 1.f/(1.f + expf(-acc));
}

// ---------------- bilinear 32x64 -> 256x512, threshold, & valid ----------------
__global__ void resizek(const float* __restrict__ m, const int* __restrict__ keep,
                        float* __restrict__ out){
  const int b = blockIdx.z, r = blockIdx.y;
  const int pid = blockIdx.x*blockDim.x + threadIdx.x;  // 0..32767
  const int y  = pid >> 7;
  const int x4 = (pid & 127) << 2;
  bool valid = keep[b*TOPK_N + r] >= 0;
  const float* mb = m + ((size_t)b*TOPK_N + r)*NANCH;
  float sy = (y + 0.5f)*0.125f - 0.5f;
  sy = fminf(fmaxf(sy, 0.f), 31.f);
  int y0 = (int)floorf(sy);
  int y1 = min(y0+1, 31);
  float wy = sy - (float)y0;
  const float* r0 = mb + y0*64;
  const float* r1 = mb + y1*64;
  float res[4];
#pragma unroll
  for (int k=0;k<4;k++){
    int x = x4 + k;
    float sx = (x + 0.5f)*0.125f - 0.5f;
    sx = fminf(fmaxf(sx, 0.f), 63.f);
    int x0 = (int)floorf(sx);
    int x1 = min(x0+1, 63);
    float wx = sx - (float)x0;
    float t0 = r0[x0]*(1.f-wy) + r1[x0]*wy;
    float t1 = r0[x1]*(1.f-wy) + r1[x1]*wy;
    float v  = t0*(1.f-wx) + t1*wx;
    res[k] = (v > 0.5f && valid) ? 1.f : 0.f;
  }
  float4 v4 = make_float4(res[0], res[1], res[2], res[3]);
  *(float4*)(out + OUT_MASKS + (((size_t)b*TOPK_N + r)*256 + y)*512 + x4) = v4;
}

extern "C" void kernel_launch(void* const* d_in, const int* in_sizes, int n_in,
                              void* d_out, int out_size, void* d_ws, size_t ws_size,
                              hipStream_t stream) {
  const float* images=(const float*)d_in[0];
  const float* w1=(const float*)d_in[1];  const float* b1=(const float*)d_in[2];
  const float* w2=(const float*)d_in[3];  const float* b2=(const float*)d_in[4];
  const float* w3=(const float*)d_in[5];  const float* b3=(const float*)d_in[6];
  const float* pw1=(const float*)d_in[7]; const float* pb1=(const float*)d_in[8];
  const float* pw2=(const float*)d_in[9]; const float* pb2=(const float*)d_in[10];
  const float* cw=(const float*)d_in[11]; const float* cb=(const float*)d_in[12];
  const float* bw=(const float*)d_in[13]; const float* bb=(const float*)d_in[14];
  const float* kw=(const float*)d_in[15]; const float* kb=(const float*)d_in[16];
  float* out = (float*)d_out;
  char* ws = (char*)d_ws;

  float* x1    = (float*)(ws + OFF_X1);
  float* x2    = (float*)(ws + OFF_X2);
  float* feat  = (float*)(ws + OFF_FEAT);
  float* p1    = (float*)(ws + OFF_P1);
  float* proto = (float*)(ws + OFF_PROTO);
  float* cls   = (float*)(ws + OFF_CLS);
  float* boxh  = (float*)(ws + OFF_BOXH);
  float* coef  = (float*)(ws + OFF_COEF);
  float* boxes = (float*)(ws + OFF_BOXES);
  float* scores= (float*)(ws + OFF_SCORES);
  int*   labels= (int*)  (ws + OFF_LABELS);
  int*   order = (int*)  (ws + OFF_ORDER);
  float* sb    = (float*)(ws + OFF_SB);
  unsigned long long* iou = (unsigned long long*)(ws + OFF_IOU);
  int*   keep  = (int*)  (ws + OFF_KEEP);
  unsigned* maxb = (unsigned*)(ws + OFF_MAXB);
  float* m     = (float*)(ws + OFF_M);

  initk<<<dim3(1), dim3(64), 0, stream>>>(maxb);

  // backbone
  convk<3,64,256,512,128,256,2,4,true>
      <<<dim3(128,16,BB), 256, 4*3*9*4, stream>>>(images, w1, b1, x1);
  convk<64,128,128,256,64,128,2,4,true>
      <<<dim3(32,32,BB), 256, 4*64*9*4, stream>>>(x1, w2, b2, x2);
  convk<128,256,64,128,32,64,2,4,true>
      <<<dim3(8,64,BB), 256, 4*128*9*4, stream>>>(x2, w3, b3, feat);

  // proto branch
  convk<256,256,32,64,32,64,1,4,true>
      <<<dim3(8,64,BB), 256, 4*256*9*4, stream>>>(feat, pw1, pb1, p1);
  pw2k<<<dim3(8,BB), 256, 0, stream>>>(p1, pw2, pb2, proto);

  // heads (channel-major outputs)
  convk<256,21,32,64,32,64,1,3,false>
      <<<dim3(8,7,BB), 256, 3*256*9*4, stream>>>(feat, cw, cb, cls);
  convk<256,4,32,64,32,64,1,4,false>
      <<<dim3(8,1,BB), 256, 4*256*9*4, stream>>>(feat, bw, bb, boxh);
  convk<256,32,32,64,32,64,1,4,false>
      <<<dim3(8,8,BB), 256, 4*256*9*4, stream>>>(feat, kw, kb, coef);

  // decode + NMS
  decodek<<<dim3(8,BB), 256, 0, stream>>>(cls, boxh, boxes, scores, labels, maxb);
  sortk<<<dim3(BB), 1024, 0, stream>>>(scores, boxes, labels, maxb, order, sb);
  ioumask<<<dim3(256,BB), 256, 0, stream>>>(sb, iou);
  nmsscan<<<dim3(BB), 64, 0, stream>>>(iou, order, keep);
  gatherk<<<dim3(BB), 128, 0, stream>>>(keep, boxes, scores, labels, out);

  // masks
  maskm<<<dim3(8,TOPK_N,BB), 256, 0, stream>>>(keep, coef, proto, m);
  resizek<<<dim3(128,TOPK_N,BB), 256, 0, stream>>>(m, keep, out);
}

// Round 2
// 1699.473 us; speedup vs baseline: 2.4380x; 2.4380x over previous
//
#include <hip/hip_runtime.h>
#include <math.h>

#define BB 8
#define NCLS 21
#define NANCH 2048
#define TOPK_N 100

// ---------------- workspace layout (bytes) ----------------
static const size_t OFF_X1    = 0;          // 8*64*128*256*4 = 67108864
static const size_t OFF_X2    = 67108864;   // 8*128*64*128*4 = 33554432
static const size_t OFF_FEAT  = 100663296;  // 8*256*32*64*4  = 16777216 (total 117440512)
// packed weights for conv1/conv2 live in the (not-yet-written) FEAT region:
static const size_t OFF_WT1   = 100663296;  // 27*64*4   = 6912
static const size_t OFF_WT2   = 100671488;  // 576*128*4 = 294912 (ends 100966400 < FEAT end)
// post-feat buffers reuse the X1 region:
static const size_t OFF_P1    = 0;          // 16777216
static const size_t OFF_PROTO = 16777216;   // 8*32*2048*4 = 2097152 -> 18874368
static const size_t OFF_HOUT  = 18874368;   // 8*64*2048*4 = 4194304 -> 23068672
static const size_t OFF_BOXES = 23068672;   // 262144 -> 23330816
static const size_t OFF_SCORES= 23330816;   // 65536  -> 23396352
static const size_t OFF_LABELS= 23396352;   // 65536  -> 23461888
static const size_t OFF_ORDER = 23461888;   // 65536  -> 23527424
static const size_t OFF_SB    = 23527424;   // 262144 -> 23789568
static const size_t OFF_IOU   = 23789568;   // 4194304-> 27983872
static const size_t OFF_KEEP  = 27983872;   // 3200
static const size_t OFF_MAXB  = 27987072;   // 32 (pad to 27987200)
static const size_t OFF_M     = 27987200;   // 6553600 -> 34540800
// packed weights for conv3/pw1/heads/pw2 (packed AFTER conv2, X1 dead by then):
static const size_t OFF_WT3   = 35651584;   // 1152*256*4 = 1179648 -> 36831232
static const size_t OFF_WTP1  = 36831232;   // 2304*256*4 = 2359296 -> 39190528
static const size_t OFF_WTH   = 39190528;   // 2304*64*4  = 589824  -> 39780352
static const size_t OFF_WTP2  = 39780352;   // 256*32*4   = 32768   -> 39813120
static const size_t OFF_BH    = 39813120;   // 64*4 -> 39813376 (< 67108864)

// ---------------- output layout (float elements) ----------------
static const size_t OUT_BOXES  = 0;
static const size_t OUT_SCORES = 3200;
static const size_t OUT_LABELS = 4000;
static const size_t OUT_MASKS  = 4800;
static const size_t OUT_VALID  = 104862400;

__device__ __forceinline__ unsigned encf(float f){
  unsigned u = __float_as_uint(f);
  return (u & 0x80000000u) ? ~u : (u | 0x80000000u);
}
__device__ __forceinline__ float decf(unsigned u){
  unsigned b = (u & 0x80000000u) ? (u & 0x7fffffffu) : ~u;
  return __uint_as_float(b);
}

__global__ void initk(unsigned* maxb){
  if (threadIdx.x < BB) maxb[threadIdx.x] = 0u;
}

// ---------------- weight pre-transpose: [co][ci][K] -> [ci*K+k][co] ----------------
template<int CIN,int COUT,int KK>
__global__ void packw(const float* __restrict__ w, float* __restrict__ wT){
  int i = blockIdx.x*256 + threadIdx.x;          // over CIN*KK*COUT (out order)
  if (i >= CIN*KK*COUT) return;
  int co = i % COUT; int r = i / COUT;           // r = ci*KK + k
  int ci = r / KK,  k = r % KK;
  wT[i] = w[(co*CIN + ci)*KK + k];
}

// pack the 3 heads (21+4+32, zero-pad to 64) into one transposed weight + bias
__global__ void packh(const float* __restrict__ cw, const float* __restrict__ bw,
                      const float* __restrict__ kw, const float* __restrict__ cb,
                      const float* __restrict__ bb, const float* __restrict__ kb,
                      float* __restrict__ wTh, float* __restrict__ bh){
  int i = blockIdx.x*256 + threadIdx.x;
  if (i < 64){
    float v = 0.f;
    if (i < 21) v = cb[i]; else if (i < 25) v = bb[i-21]; else if (i < 57) v = kb[i-25];
    bh[i] = v;
  }
  if (i >= 2304*64) return;
  int co = i & 63; int r = i >> 6;               // r = ci*9+k
  int ci = r/9, k = r%9;
  float v = 0.f;
  if (co < 21)      v = cw[(co*256 + ci)*9 + k];
  else if (co < 25) v = bw[((co-21)*256 + ci)*9 + k];
  else if (co < 57) v = kw[((co-25)*256 + ci)*9 + k];
  wTh[i] = v;
}

// ---------------- register-blocked direct conv ----------------
// thread computes COPT output channels x SPT consecutive-x outputs.
// weights pre-transposed to [ci*9+k][COUT] -> wave-uniform s_load_dwordx16.
template<int CIN,int COUT,int H,int W,int OH,int OW,int S,int COPT,int SPT,bool RELU>
__global__ __launch_bounds__(256) void convk2(const float* __restrict__ in,
    const float* __restrict__ wT, const float* __restrict__ bias,
    float* __restrict__ out){
  constexpr int NC = S*(SPT-1) + 3;              // input cols touched per row
  const int b   = blockIdx.z;
  const int co0 = blockIdx.y * COPT;
  const int g   = blockIdx.x*blockDim.x + threadIdx.x;   // spatial group
  constexpr int GPR = OW / SPT;
  const int y  = g / GPR;
  const int x0 = (g - y*GPR) * SPT;

  float acc[COPT][SPT];
#pragma unroll
  for (int c=0;c<COPT;c++){
    float bv = bias[co0+c];
#pragma unroll
    for (int s=0;s<SPT;s++) acc[c][s] = bv;
  }

  // precompute clamped offsets + 0/1 masks (loads always in-bounds, no exec juggling)
  int   off[3][NC];
  float msk[3][NC];
#pragma unroll
  for (int kh=0;kh<3;kh++){
    int iy = y*S - 1 + kh;
    bool okr = (iy >= 0) && (iy < H);
    int ro = okr ? iy*W : 0;
#pragma unroll
    for (int t=0;t<NC;t++){
      int col = x0*S - 1 + t;
      bool ok = okr && (col >= 0) && (col < W);
      off[kh][t] = ok ? (ro + col) : 0;
      msk[kh][t] = ok ? 1.f : 0.f;
    }
  }

  const float* inb = in + (size_t)b*CIN*H*W;
  const float* wb  = wT + co0;
  for (int ci=0; ci<CIN; ci++){
    const float* inc = inb + (size_t)ci*H*W;
    float v[3][NC];
#pragma unroll
    for (int kh=0;kh<3;kh++)
#pragma unroll
      for (int t=0;t<NC;t++)
        v[kh][t] = inc[off[kh][t]] * msk[kh][t];
    const float* wp = wb + (size_t)ci*9*COUT;
#pragma unroll
    for (int kh=0;kh<3;kh++)
#pragma unroll
    for (int kw=0;kw<3;kw++){
      const float* wq = wp + (kh*3+kw)*COUT;     // uniform address -> s_load
#pragma unroll
      for (int c=0;c<COPT;c++){
        float wv = wq[c];
#pragma unroll
        for (int s=0;s<SPT;s++)
          acc[c][s] = fmaf(wv, v[kh][S*s+kw], acc[c][s]);
      }
    }
  }

#pragma unroll
  for (int c=0;c<COPT;c++){
    float* op = out + ((size_t)b*COUT + co0 + c)*((size_t)OH*OW) + y*OW + x0;
#pragma unroll
    for (int s=0;s<SPT;s++){
      float r = acc[c][s];
      if (RELU) r = fmaxf(r, 0.f);
      op[s] = r;
    }
  }
}

// ---------------- 1x1 conv 256->32 with transposed weights ----------------
__global__ __launch_bounds__(256) void pw2k2(const float* __restrict__ p1,
    const float* __restrict__ wT, const float* __restrict__ bias,
    float* __restrict__ proto){
  const int b  = blockIdx.y;
  const int sp = blockIdx.x*256 + threadIdx.x;
  float acc[32];
#pragma unroll
  for (int c=0;c<32;c++) acc[c] = bias[c];
  const float* pb = p1 + (size_t)b*256*NANCH + sp;
  for (int ci=0;ci<256;ci++){
    float v = pb[(size_t)ci*NANCH];
    const float* wq = wT + ci*32;                // uniform -> s_load
#pragma unroll
    for (int c=0;c<32;c++) acc[c] = fmaf(v, wq[c], acc[c]);
  }
#pragma unroll
  for (int c=0;c<32;c++)
    proto[((size_t)b*32 + c)*NANCH + sp] = acc[c];
}

// ---------------- decode: softmax/labels/boxes + per-batch max(boxes) ----------------
__global__ void decodek(const float* __restrict__ hout,
                        float* __restrict__ boxes, float* __restrict__ scores,
                        int* __restrict__ labels, unsigned* __restrict__ maxb){
  const int b = blockIdx.y;
  const int n = blockIdx.x*blockDim.x + threadIdx.x;  // 0..2047
  const float* cp = hout + (size_t)b*64*NANCH + n;    // channel stride NANCH
  float l[NCLS];
  float M = -1e30f;
#pragma unroll
  for (int c=0;c<NCLS;c++){ l[c] = cp[(size_t)c*NANCH]; M = fmaxf(M, l[c]); }
  float denom = 0.f;
#pragma unroll
  for (int c=0;c<NCLS;c++) denom += expf(l[c]-M);
  float best = -1.f; int bi = 0;
#pragma unroll
  for (int c=0;c<NCLS-1;c++){
    float e = expf(l[c]-M);
    if (e > best){ best = e; bi = c; }
  }
  scores[(size_t)b*NANCH + n] = best/denom;
  labels[(size_t)b*NANCH + n] = bi;

  float dx = cp[21*(size_t)NANCH], dy = cp[22*(size_t)NANCH];
  float dw = cp[23*(size_t)NANCH], dh = cp[24*(size_t)NANCH];
  const int yy = n >> 6, xx = n & 63;
  float cx = (xx+0.5f)*8.f, cy = (yy+0.5f)*8.f;
  float px = cx + dx*32.f, py = cy + dy*32.f;
  float pw = 32.f*expf(dw), ph = 32.f*expf(dh);
  float x1 = px - 0.5f*pw, y1 = py - 0.5f*ph;
  float x2 = px + 0.5f*pw, y2 = py + 0.5f*ph;
  float* bo = boxes + ((size_t)b*NANCH + n)*4;
  bo[0]=x1; bo[1]=y1; bo[2]=x2; bo[3]=y2;
  float mx = fmaxf(fmaxf(x1,y1), fmaxf(x2,y2));
#pragma unroll
  for (int off=32; off>0; off>>=1) mx = fmaxf(mx, __shfl_down(mx, off));
  if ((threadIdx.x & 63) == 0) atomicMax(maxb + b, encf(mx));
}

// ---------------- stable descending sort (bitonic, idx tiebreak) ----------------
__global__ void __launch_bounds__(1024) sortk(const float* __restrict__ scores,
                     const float* __restrict__ boxes, const int* __restrict__ labels,
                     const unsigned* __restrict__ maxb,
                     int* __restrict__ order, float* __restrict__ sb){
  __shared__ float sc[NANCH];
  __shared__ int   id[NANCH];
  const int b = blockIdx.x, t = threadIdx.x;
  for (int i=t;i<NANCH;i+=1024){ sc[i]=scores[(size_t)b*NANCH+i]; id[i]=i; }
  __syncthreads();
  for (int k=2;k<=NANCH;k<<=1){
    for (int j=k>>1;j>0;j>>=1){
      for (int i=t;i<NANCH;i+=1024){
        int ixj = i ^ j;
        if (ixj > i){
          float sa=sc[i], sb_=sc[ixj]; int ia=id[i], ib=id[ixj];
          bool dir = ((i & k) == 0);
          bool before_ba = (sb_ > sa) || (sb_ == sa && ib < ia);
          if (before_ba == dir){ sc[i]=sb_; sc[ixj]=sa; id[i]=ib; id[ixj]=ia; }
        }
      }
      __syncthreads();
    }
  }
  float mboff = decf(maxb[b]) + 1.0f;
  for (int r=t;r<NANCH;r+=1024){
    int o = id[r];
    order[(size_t)b*NANCH + r] = o;
    float off = (float)labels[(size_t)b*NANCH + o] * mboff;
    const float* bo = boxes + ((size_t)b*NANCH + o)*4;
    float* sp = sb + ((size_t)b*NANCH + r)*4;
    sp[0]=bo[0]+off; sp[1]=bo[1]+off; sp[2]=bo[2]+off; sp[3]=bo[3]+off;
  }
}

// ---------------- IoU>thr bitmask ----------------
__global__ void ioumask(const float* __restrict__ sb, unsigned long long* __restrict__ iou){
  const int b = blockIdx.y;
  const int gid = blockIdx.x*blockDim.x + threadIdx.x;  // 0..65535
  const int i = gid >> 5, w = gid & 31;
  const float* base = sb + (size_t)b*NANCH*4;
  unsigned long long bits = 0ull;
  const int j0 = w << 6;
  if (j0 + 63 > i){
    float x1=base[i*4], y1=base[i*4+1], x2=base[i*4+2], y2=base[i*4+3];
    float ai = (x2-x1)*(y2-y1);
    for (int jj=0;jj<64;jj++){
      int j = j0 + jj;
      if (j > i){
        float bx1=base[j*4], by1=base[j*4+1], bx2=base[j*4+2], by2=base[j*4+3];
        float lx=fmaxf(x1,bx1), ly=fmaxf(y1,by1);
        float rx=fminf(x2,bx2), ry=fminf(y2,by2);
        float ww=fmaxf(rx-lx,0.f), hh=fmaxf(ry-ly,0.f);
        float inter = ww*hh;
        float aj = (bx2-bx1)*(by2-by1);
        float v = inter/(ai + aj - inter + 1e-9f);
        if (v > 0.5f) bits |= (1ull << jj);
      }
    }
  }
  iou[((size_t)b*NANCH + i)*32 + w] = bits;
}

// ---------------- greedy NMS scan ----------------
__global__ void nmsscan(const unsigned long long* __restrict__ iou,
                        const int* __restrict__ order, int* __restrict__ keep){
  const int b = blockIdx.x, lane = threadIdx.x;
  unsigned long long sup = 0ull;
  int k = 0;
  for (int i=0; i<NANCH && k<TOPK_N; i++){
    int wi = i >> 6, bi = i & 63;
    unsigned long long wv = __shfl(sup, wi);
    if (!((wv >> bi) & 1ull)){
      if (lane == 0) keep[b*TOPK_N + k] = order[(size_t)b*NANCH + i];
      k++;
      unsigned long long row = (lane < 32) ? iou[((size_t)b*NANCH + i)*32 + lane] : 0ull;
      sup |= row;
    }
  }
  for (int r = lane; r < TOPK_N; r += 64)
    if (r >= k) keep[b*TOPK_N + r] = -1;
}

// ---------------- gather kept results ----------------
__global__ void gatherk(const int* __restrict__ keep, const float* __restrict__ boxes,
                        const float* __restrict__ scores, const int* __restrict__ labels,
                        float* __restrict__ out){
  const int b = blockIdx.x, r = threadIdx.x;
  if (r >= TOPK_N) return;
  int ki = keep[b*TOPK_N + r];
  float valid = (ki >= 0) ? 1.f : 0.f;
  int kc = (ki < 0) ? 0 : ki;
  const float* bo = boxes + ((size_t)b*NANCH + kc)*4;
#pragma unroll
  for (int c=0;c<4;c++) out[OUT_BOXES + ((size_t)b*TOPK_N + r)*4 + c] = bo[c]*valid;
  out[OUT_SCORES + b*TOPK_N + r] = scores[(size_t)b*NANCH + kc]*valid;
  out[OUT_LABELS + b*TOPK_N + r] = (ki >= 0) ? (float)labels[(size_t)b*NANCH + kc] : 0.f;
  out[OUT_VALID  + b*TOPK_N + r] = valid;
}

// ---------------- mask logits + sigmoid ----------------
__global__ void maskm(const int* __restrict__ keep, const float* __restrict__ hout,
                      const float* __restrict__ proto, float* __restrict__ m){
  const int b = blockIdx.z, r = blockIdx.y;
  const int s = blockIdx.x*blockDim.x + threadIdx.x;
  __shared__ float cf[32];
  int ki = keep[b*TOPK_N + r];
  int kc = (ki < 0) ? 0 : ki;
  if (threadIdx.x < 32)
    cf[threadIdx.x] = hout[((size_t)b*64 + 25 + threadIdx.x)*NANCH + kc];
  __syncthreads();
  float acc = 0.f;
#pragma unroll
  for (int p=0;p<32;p++) acc = fmaf(cf[p], proto[((size_t)b*32 + p)*NANCH + s], acc);
  m[((size_t)b*TOPK_N + r)*NANCH + s] = 1.f/(1.f + expf(-acc));
}

// ---------------- bilinear 32x64 -> 256x512, threshold ----------------
__global__ void resizek(const float* __restrict__ m, const int* __restrict__ keep,
                        float* __restrict__ out){
  const int b = blockIdx.z, r = blockIdx.y;
  const int pid = blockIdx.x*blockDim.x + threadIdx.x;
  const int y  = pid >> 7;
  const int x4 = (pid & 127) << 2;
  bool valid = keep[b*TOPK_N + r] >= 0;
  const float* mb = m + ((size_t)b*TOPK_N + r)*NANCH;
  float sy = (y + 0.5f)*0.125f - 0.5f;
  sy = fminf(fmaxf(sy, 0.f), 31.f);
  int y0 = (int)floorf(sy);
  int y1 = min(y0+1, 31);
  float wy = sy - (float)y0;
  const float* r0 = mb + y0*64;
  const float* r1 = mb + y1*64;
  float res[4];
#pragma unroll
  for (int k=0;k<4;k++){
    int x = x4 + k;
    float sx = (x + 0.5f)*0.125f - 0.5f;
    sx = fminf(fmaxf(sx, 0.f), 63.f);
    int x0 = (int)floorf(sx);
    int x1 = min(x0+1, 63);
    float wx = sx - (float)x0;
    float t0 = r0[x0]*(1.f-wy) + r1[x0]*wy;
    float t1 = r0[x1]*(1.f-wy) + r1[x1]*wy;
    float v  = t0*(1.f-wx) + t1*wx;
    res[k] = (v > 0.5f && valid) ? 1.f : 0.f;
  }
  float4 v4 = make_float4(res[0], res[1], res[2], res[3]);
  *(float4*)(out + OUT_MASKS + (((size_t)b*TOPK_N + r)*256 + y)*512 + x4) = v4;
}

extern "C" void kernel_launch(void* const* d_in, const int* in_sizes, int n_in,
                              void* d_out, int out_size, void* d_ws, size_t ws_size,
                              hipStream_t stream) {
  const float* images=(const float*)d_in[0];
  const float* w1=(const float*)d_in[1];  const float* b1=(const float*)d_in[2];
  const float* w2=(const float*)d_in[3];  const float* b2=(const float*)d_in[4];
  const float* w3=(const float*)d_in[5];  const float* b3=(const float*)d_in[6];
  const float* pw1=(const float*)d_in[7]; const float* pb1=(const float*)d_in[8];
  const float* pw2=(const float*)d_in[9]; const float* pb2=(const float*)d_in[10];
  const float* cw=(const float*)d_in[11]; const float* cb=(const float*)d_in[12];
  const float* bw=(const float*)d_in[13]; const float* bb=(const float*)d_in[14];
  const float* kw=(const float*)d_in[15]; const float* kb=(const float*)d_in[16];
  float* out = (float*)d_out;
  char* ws = (char*)d_ws;

  float* x1    = (float*)(ws + OFF_X1);
  float* x2    = (float*)(ws + OFF_X2);
  float* feat  = (float*)(ws + OFF_FEAT);
  float* wT1   = (float*)(ws + OFF_WT1);
  float* wT2   = (float*)(ws + OFF_WT2);
  float* wT3   = (float*)(ws + OFF_WT3);
  float* wTp1  = (float*)(ws + OFF_WTP1);
  float* wTh   = (float*)(ws + OFF_WTH);
  float* wTp2  = (float*)(ws + OFF_WTP2);
  float* bh    = (float*)(ws + OFF_BH);
  float* p1    = (float*)(ws + OFF_P1);
  float* proto = (float*)(ws + OFF_PROTO);
  float* hout  = (float*)(ws + OFF_HOUT);
  float* boxes = (float*)(ws + OFF_BOXES);
  float* scores= (float*)(ws + OFF_SCORES);
  int*   labels= (int*)  (ws + OFF_LABELS);
  int*   order = (int*)  (ws + OFF_ORDER);
  float* sb    = (float*)(ws + OFF_SB);
  unsigned long long* iou = (unsigned long long*)(ws + OFF_IOU);
  int*   keep  = (int*)  (ws + OFF_KEEP);
  unsigned* maxb = (unsigned*)(ws + OFF_MAXB);
  float* m     = (float*)(ws + OFF_M);

  initk<<<dim3(1), dim3(64), 0, stream>>>(maxb);

  // pack conv1/conv2 weights into the (still-unwritten) FEAT region
  packw<3,64,9>  <<<dim3(7),   256, 0, stream>>>(w1, wT1);
  packw<64,128,9><<<dim3(288), 256, 0, stream>>>(w2, wT2);

  // backbone
  convk2<3,64,256,512,128,256,2,16,2,true>
      <<<dim3(64,4,BB), 256, 0, stream>>>(images, wT1, b1, x1);
  convk2<64,128,128,256,64,128,2,16,2,true>
      <<<dim3(16,8,BB), 256, 0, stream>>>(x1, wT2, b2, x2);

  // x1 is dead now: pack remaining weights into its upper region
  packw<128,256,9><<<dim3(1152), 256, 0, stream>>>(w3, wT3);
  packw<256,256,9><<<dim3(2304), 256, 0, stream>>>(pw1, wTp1);
  packh<<<dim3(576), 256, 0, stream>>>(cw, bw, kw, cb, bb, kb, wTh, bh);
  packw<256,32,1> <<<dim3(32),   256, 0, stream>>>(pw2, wTp2);

  convk2<128,256,64,128,32,64,2,16,2,true>
      <<<dim3(4,16,BB), 256, 0, stream>>>(x2, wT3, b3, feat);

  // proto branch
  convk2<256,256,32,64,32,64,1,16,2,true>
      <<<dim3(4,16,BB), 256, 0, stream>>>(feat, wTp1, pb1, p1);
  pw2k2<<<dim3(8,BB), 256, 0, stream>>>(p1, wTp2, pb2, proto);

  // fused heads: 64 packed channels (21 cls | 4 box | 32 coef | 7 pad)
  convk2<256,64,32,64,32,64,1,16,1,false>
      <<<dim3(8,4,BB), 256, 0, stream>>>(feat, wTh, bh, hout);

  // decode + NMS
  decodek<<<dim3(8,BB), 256, 0, stream>>>(hout, boxes, scores, labels, maxb);
  sortk<<<dim3(BB), 1024, 0, stream>>>(scores, boxes, labels, maxb, order, sb);
  ioumask<<<dim3(256,BB), 256, 0, stream>>>(sb, iou);
  nmsscan<<<dim3(BB), 64, 0, stream>>>(iou, order, keep);
  gatherk<<<dim3(BB), 128, 0, stream>>>(keep, boxes, scores, labels, out);

  // masks
  maskm<<<dim3(8,TOPK_N,BB), 256, 0, stream>>>(keep, hout, proto, m);
  resizek<<<dim3(128,TOPK_N,BB), 256, 0, stream>>>(m, keep, out);
}